// Round 8
// baseline (255.423 us; speedup 1.0000x reference)
//
#include <hip/hip_runtime.h>
#include <hip/hip_bf16.h>
#include <math.h>

#define KCOMP 32
#define DDIM  128
#define NPTS  65536
#define GMM_EPS 1e-6f
#define SA 129   // LDS row stride (odd -> conflict-free for scalar col access)
#define UCH 9    // U frag chunks per k: 8 real K-chunks + 1 augmentation (-m')
#define USTRIDE (UCH*256)   // uint4 per component

typedef __attribute__((ext_vector_type(8)))  __bf16 bf16x8;
typedef __attribute__((ext_vector_type(16))) float  f32x16;

__device__ __forceinline__ unsigned short f2bf(float f){
  unsigned u = __builtin_bit_cast(unsigned, f);
  u = (u + 0x7FFFu + ((u >> 16) & 1u)) >> 16;   // RNE
  return (unsigned short)u;
}
// v_readlane_b32: VALU->SGPR broadcast, ~2-4 cyc, NO LDS round trip.
__device__ __forceinline__ float rlane(float v, int lsrc){
  return __builtin_bit_cast(float, __builtin_amdgcn_readlane(__builtin_bit_cast(int, v), lsrc));
}

// ---------------------------------------------------------------------------
// chol_inv32: register-resident Cholesky + triangular inverse of one 32x32
// SPD block. One wave; lane c = column c. All indices compile-time (pure
// VGPR); all cross-lane via v_readlane (ds_bpermute cost 100us in round 6).
// ---------------------------------------------------------------------------
__device__ __noinline__ float chol_inv32(float* __restrict__ Ab,
                                         float* __restrict__ Wb,
                                         const int c){
  float ar[32], lr[32], rd[32], v[32];
  #pragma unroll
  for(int i=0;i<32;i++) ar[i] = Ab[i*SA + c];   // column c (symmetric block)
  float hl = 0.f;
  #pragma unroll
  for(int j=0;j<32;j++){
    float d   = rlane(ar[j], j);        // Schur diag = L[j][j]^2
    float rsd = rsqrtf(d);
    hl += logf(d);
    rd[j] = rsd;
    float Lcj  = ar[j]*rsd;             // L[c][j] (valid for c>=j)
    lr[j] = (c>=j) ? Lcj : 0.f;
    float coef = Lcj*rsd;
    #pragma unroll
    for(int i=j;i<32;i++){
      float bij = rlane(ar[i], j);
      ar[i] = fmaf(-bij, coef, ar[i]);
    }
  }
  #pragma unroll
  for(int j=0;j<32;j++) Ab[c*SA + j] = lr[j];
  #pragma unroll
  for(int i=0;i<32;i++){
    float s = (i==c) ? 1.f : 0.f;
    #pragma unroll
    for(int p=0;p<i;p++) s = fmaf(-rlane(lr[p], i), v[p], s);
    v[i] = s * rd[i];
  }
  #pragma unroll
  for(int i=0;i<32;i++) Wb[i*SA + c] = v[i];
  return 0.5f*hl;
}

// ---------------------------------------------------------------------------
// k_prep: one block (256 thr) per component. Blocked Cholesky+inverse;
// panel solve & SYRK & inverse-levels as 4x4 reg-tiled LDS GEMMs; then m',
// const2, and bf16 MFMA A-frag pack WITH augmentation chunk 8 = -m' column.
// ---------------------------------------------------------------------------
__global__ __launch_bounds__(256) void k_prep(const float* __restrict__ cov,
                                              const float* __restrict__ wts,
                                              const float* __restrict__ means,
                                              float* __restrict__ ws_c2,
                                              unsigned short* __restrict__ ufrag){
  __shared__ float A[DDIM*SA];      // 64.5 KB: cov -> L (lower)
  __shared__ float W[DDIM*SA];      // 64.5 KB: U = L^{-1} (lower), 0 above
  __shared__ float Tb[3*32*33];     // level-GEMM scratch; later m' [0..127]
  __shared__ float muS[DDIM];
  const int t=threadIdx.x, w=t>>6, l=t&63, k=blockIdx.x;
  const int r0=(l>>3)*4, c0=(l&7)*4;

  const float4* cv4 = (const float4*)(cov + (size_t)k*DDIM*DDIM);
  #pragma unroll
  for(int v=0; v<16; v++){
    int idx4 = t + 256*v; float4 f = cv4[idx4];
    int e = idx4*4; int i = e>>7; int j = e&127;
    float* d = &A[i*SA+j]; d[0]=f.x; d[1]=f.y; d[2]=f.z; d[3]=f.w;
  }
  for(int z=t; z<DDIM*SA; z+=256) W[z] = 0.f;
  if(t<DDIM) muS[t] = means[k*DDIM+t];
  __syncthreads();
  if(t<DDIM) A[t*SA+t] += GMM_EPS;
  __syncthreads();

  static const int SYI[10]={1,2,2,3,3,3, 2,3,3, 3};
  static const int SYJ[10]={1,1,2,1,2,3, 2,2,3, 3};
  static const int SYO[5] ={0,6,9,10,10};

  float hsum = 0.f;
  #pragma unroll 1
  for(int b=0;b<4;b++){
    const int b32=b*32;
    if(w==0) hsum += chol_inv32(&A[b32*SA+b32], &W[b32*SA+b32], l&31);
    __syncthreads();
    if(w < 3-b){
      const int ibl = b+1+w;
      float acc[4][4]={};
      for(int kc=0;kc<32;kc+=4){
        float a_[4][4], b_[4][4];
        #pragma unroll
        for(int e=0;e<4;e++)
          #pragma unroll
          for(int g=0;g<4;g++){
            a_[e][g]=A[(32*ibl+r0+e)*SA + b32+kc+g];
            b_[e][g]=W[(b32+c0+e)*SA   + b32+kc+g];
          }
        #pragma unroll
        for(int e=0;e<4;e++)
          #pragma unroll
          for(int f=0;f<4;f++)
            acc[e][f]+=a_[e][0]*b_[f][0]+a_[e][1]*b_[f][1]
                      +a_[e][2]*b_[f][2]+a_[e][3]*b_[f][3];
      }
      #pragma unroll
      for(int e=0;e<4;e++)
        #pragma unroll
        for(int f=0;f<4;f++)
          A[(32*ibl+r0+e)*SA + b32+c0+f] = acc[e][f];
    }
    __syncthreads();
    #pragma unroll 1
    for(int u=SYO[b]+w; u<SYO[b+1]; u+=4){
      const int ui=SYI[u], uj=SYJ[u];
      float acc[4][4]={};
      for(int kc=0;kc<32;kc+=4){
        float a_[4][4], b_[4][4];
        #pragma unroll
        for(int e=0;e<4;e++)
          #pragma unroll
          for(int g=0;g<4;g++){
            a_[e][g]=A[(32*ui+r0+e)*SA + b32+kc+g];
            b_[e][g]=A[(32*uj+c0+e)*SA + b32+kc+g];
          }
        #pragma unroll
        for(int e=0;e<4;e++)
          #pragma unroll
          for(int f=0;f<4;f++)
            acc[e][f]+=a_[e][0]*b_[f][0]+a_[e][1]*b_[f][1]
                      +a_[e][2]*b_[f][2]+a_[e][3]*b_[f][3];
      }
      #pragma unroll
      for(int e=0;e<4;e++)
        #pragma unroll
        for(int f=0;f<4;f++)
          A[(32*ui+r0+e)*SA+32*uj+c0+f] -= acc[e][f];
    }
    __syncthreads();
  }

  #pragma unroll 1
  for(int lev=1;lev<=3;lev++){
    if(w<4-lev){
      const int j=w, i=w+lev;
      float* T=&Tb[w*1056];
      float acc[4][4]={};
      #pragma unroll 1
      for(int p=j;p<i;p++){
        for(int kc=0;kc<32;kc+=4){
          float a_[4][4], b_[4][4];
          #pragma unroll
          for(int e=0;e<4;e++)
            #pragma unroll
            for(int g=0;g<4;g++){
              a_[e][g]=A[(32*i+r0+e)*SA + 32*p+kc+g];
              b_[e][g]=W[(32*p+kc+e)*SA + 32*j+c0+g];
            }
          #pragma unroll
          for(int e=0;e<4;e++)
            #pragma unroll
            for(int f=0;f<4;f++)
              acc[e][f]+=a_[e][0]*b_[0][f]+a_[e][1]*b_[1][f]
                        +a_[e][2]*b_[2][f]+a_[e][3]*b_[3][f];
        }
      }
      #pragma unroll
      for(int e=0;e<4;e++)
        #pragma unroll
        for(int f=0;f<4;f++)
          T[(r0+e)*33+c0+f]=acc[e][f];
      float ac2[4][4]={};
      for(int kc=0;kc<32;kc+=4){
        float a_[4][4], b_[4][4];
        #pragma unroll
        for(int e=0;e<4;e++)
          #pragma unroll
          for(int g=0;g<4;g++){
            a_[e][g]=W[(32*i+r0+e)*SA + 32*i+kc+g];
            b_[e][g]=T[(kc+e)*33 + c0+g];
          }
        #pragma unroll
        for(int e=0;e<4;e++)
          #pragma unroll
          for(int f=0;f<4;f++)
            ac2[e][f]+=a_[e][0]*b_[0][f]+a_[e][1]*b_[1][f]
                      +a_[e][2]*b_[2][f]+a_[e][3]*b_[3][f];
      }
      #pragma unroll
      for(int e=0;e<4;e++)
        #pragma unroll
        for(int f=0;f<4;f++)
          W[(32*i+r0+e)*SA+32*j+c0+f] = -ac2[e][f];
    }
    __syncthreads();
  }

  // ---- m' = U*mu into Tb[0..127]; const2; pack 9-chunk bf16 A-frags ----
  if(t<DDIM){
    float s=0.f;
    #pragma unroll 8
    for(int c=0;c<DDIM;c++) s += W[t*SA+c]*muS[c];
    Tb[t]=s;
  }
  if(t==0) ws_c2[k] = logf(wts[k]) - hsum - 117.6241322f;
  __syncthreads();
  #pragma unroll 1
  for(int s0=t;s0<USTRIDE;s0+=256){
    uint4 wv;
    if(s0 < 2048){
      int l2=s0&63, dt2=(s0>>6)&3, kc=s0>>8;
      int row=dt2*32+(l2&31), colb=kc*16+((l2>>5)<<3);
      unsigned uu[4];
      #pragma unroll
      for(int h2=0;h2<4;h2++){
        unsigned lo=f2bf(W[row*SA+colb+2*h2]);
        unsigned hi=f2bf(W[row*SA+colb+2*h2+1]);
        uu[h2]=lo|(hi<<16);
      }
      wv.x=uu[0]; wv.y=uu[1]; wv.z=uu[2]; wv.w=uu[3];
    } else {
      // augmentation chunk: U[row][128] = -m'[row]; cols 129..143 = 0
      int r=s0-2048, l2=r&63, dt2=(r>>6)&3;
      int row=dt2*32+(l2&31);
      float val = (l2<32) ? -Tb[row] : 0.f;
      wv.x=(unsigned)f2bf(val); wv.y=0u; wv.z=0u; wv.w=0u;
    }
    ((uint4*)ufrag)[(size_t)k*USTRIDE+s0]=wv;
  }
}

// ---------------------------------------------------------------------------
// k_main: 256 thr = 4 waves = d-tiles; full-K (augmented, 9 chunks) per wave;
// X register-resident; U streamed from L2 (even/odd double buffer); waves
// walk k in STAGGERED order (dephasing: MFMA pipe stays fed); epilogue is
// pure self-dot + unconditional ds_add from all 64 lanes (q-halves cover
// disjoint d-rows) — zero cross-lane ops, zero m' reads.
// ---------------------------------------------------------------------------
#define MAIN_BODY(UR, KK)                                                     \
  {                                                                           \
    const int kidx = (KK);                                                    \
    _Pragma("unroll")                                                         \
    for(int g=0; g<2; g++){                                                   \
      f32x16 a0 = {}, a1 = {};                                                \
      _Pragma("unroll")                                                       \
      for(int c=0; c<8; c++){                                                 \
        bf16x8 af = __builtin_bit_cast(bf16x8, UR[c]);                        \
        a0 = __builtin_amdgcn_mfma_f32_32x32x16_bf16(af, xf[2*g  ][c], a0, 0,0,0); \
        a1 = __builtin_amdgcn_mfma_f32_32x32x16_bf16(af, xf[2*g+1][c], a1, 0,0,0); \
      }                                                                       \
      {                                                                       \
        bf16x8 af = __builtin_bit_cast(bf16x8, UR[8]);                        \
        a0 = __builtin_amdgcn_mfma_f32_32x32x16_bf16(af, xf8, a0, 0,0,0);     \
        a1 = __builtin_amdgcn_mfma_f32_32x32x16_bf16(af, xf8, a1, 0,0,0);     \
      }                                                                       \
      float p0=0.f,p1=0.f,p2=0.f,p3=0.f, e0=0.f,e1=0.f,e2=0.f,e3=0.f;         \
      _Pragma("unroll")                                                       \
      for(int r=0;r<16;r+=4){                                                 \
        p0=fmaf(a0[r  ],a0[r  ],p0); e0=fmaf(a1[r  ],a1[r  ],e0);             \
        p1=fmaf(a0[r+1],a0[r+1],p1); e1=fmaf(a1[r+1],a1[r+1],e1);             \
        p2=fmaf(a0[r+2],a0[r+2],p2); e2=fmaf(a1[r+2],a1[r+2],e2);             \
        p3=fmaf(a0[r+3],a0[r+3],p3); e3=fmaf(a1[r+3],a1[r+3],e3);             \
      }                                                                       \
      float s0=(p0+p1)+(p2+p3), s1=(e0+e1)+(e2+e3);                           \
      atomicAdd(&maha[kidx*DDIM + (2*g  )*32 + ln], s0);                      \
      atomicAdd(&maha[kidx*DDIM + (2*g+1)*32 + ln], s1);                      \
    }                                                                         \
  }

__global__ __launch_bounds__(256,2) void k_main(const float* __restrict__ x,
                                                const uint4* __restrict__ uf,
                                                const float* __restrict__ ws_c2,
                                                float* __restrict__ out){
  __shared__ float maha[KCOMP*DDIM];   // 16 KB [k][n]
  __shared__ float c2s[KCOMP];
  const int t = threadIdx.x, lane = t&63, dt = t>>6;
  const int q = lane>>5, ln = lane&31;
  const size_t n0 = (size_t)blockIdx.x * 128;

  {
    float4 z = {0.f,0.f,0.f,0.f};
    float4* mz = (float4*)maha;
    mz[t] = z; mz[t+256] = z; mz[t+512] = z; mz[t+768] = z;
    if(t < KCOMP) c2s[t] = ws_c2[t];
  }

  // X -> bf16 B-frags in registers (dup across waves)
  bf16x8 xf[4][8];
  {
    const float* xb = x + n0*DDIM + 8*q;
    #pragma unroll
    for(int it=0; it<4; it++){
      const float* rowp = xb + (size_t)(it*32 + ln)*DDIM;
      #pragma unroll
      for(int c=0; c<8; c++){
        float4 f0 = *(const float4*)(rowp + c*16);
        float4 f1 = *(const float4*)(rowp + c*16 + 4);
        union { unsigned short us[8]; bf16x8 v; } cvt;
        cvt.us[0]=f2bf(f0.x); cvt.us[1]=f2bf(f0.y); cvt.us[2]=f2bf(f0.z); cvt.us[3]=f2bf(f0.w);
        cvt.us[4]=f2bf(f1.x); cvt.us[5]=f2bf(f1.y); cvt.us[6]=f2bf(f1.z); cvt.us[7]=f2bf(f1.w);
        xf[it][c] = cvt.v;
      }
    }
  }
  // augmentation B-frag: k-slot 128 (q==0, jj==0) = 1.0, else 0
  bf16x8 xf8;
  {
    uint4 x8u; x8u.x = (q==0) ? 0x00003F80u : 0u; x8u.y=0u; x8u.z=0u; x8u.w=0u;
    xf8 = __builtin_bit_cast(bf16x8, x8u);
  }

  // staggered k order: dephases the 8 resident waves per CU
  const int kst = dt*8 + (int)(blockIdx.x&1)*4;

  uint4 uA[UCH], uB[UCH];
  #pragma unroll
  for(int c=0; c<UCH; c++)
    uA[c] = uf[(size_t)kst*USTRIDE + c*256 + dt*64 + lane];
  __syncthreads();

  #pragma unroll 1
  for(int i=0;i<KCOMP;i+=2){
    const int kA=(kst+i)&31, kB=(kst+i+1)&31, kN=(kst+i+2)&31;
    #pragma unroll
    for(int c=0; c<UCH; c++)
      uB[c] = uf[(size_t)kB*USTRIDE + c*256 + dt*64 + lane];
    MAIN_BODY(uA, kA)
    #pragma unroll
    for(int c=0; c<UCH; c++)
      uA[c] = uf[(size_t)kN*USTRIDE + c*256 + dt*64 + lane];
    MAIN_BODY(uB, kB)
  }
  __syncthreads();

  if(t < 128){
    float m_run = -INFINITY, s_run = 0.f;
    #pragma unroll 1
    for(int k=0;k<KCOMP;k++){
      float a  = c2s[k] - 0.5f*maha[k*DDIM + t];
      float nm = fmaxf(m_run, a);
      s_run = s_run*__expf(m_run-nm) + __expf(a-nm);
      m_run = nm;
    }
    out[n0 + t] = m_run + logf(s_run);
  }
}

// ---------------------------------------------------------------------------
extern "C" void kernel_launch(void* const* d_in, const int* in_sizes, int n_in,
                              void* d_out, int out_size, void* d_ws, size_t ws_size,
                              hipStream_t stream){
  const float* x   = (const float*)d_in[0];
  const float* mu  = (const float*)d_in[1];
  const float* cov = (const float*)d_in[2];
  const float* wts = (const float*)d_in[3];
  float* out = (float*)d_out;
  char*  ws  = (char*)d_ws;

  float*          wsC2 = (float*)(ws);                 // 128 B (const2)
  unsigned short* wsUF = (unsigned short*)(ws + 256);  // 1.18 MB (U bf16 frags, 9 chunks)

  k_prep<<<KCOMP, 256, 0, stream>>>(cov, wts, mu, wsC2, wsUF);
  k_main<<<NPTS/128, 256, 0, stream>>>(x, (const uint4*)wsUF, wsC2, out);
}